// Round 6
// baseline (406.098 us; speedup 1.0000x reference)
//
#include <hip/hip_runtime.h>
#include <hip/hip_bf16.h>

typedef unsigned int u32;
typedef unsigned short u16;
typedef short bf16x8 __attribute__((ext_vector_type(8)));
typedef float f32x4 __attribute__((ext_vector_type(4)));

static __device__ __forceinline__ float bf_lo(u32 v) { return __uint_as_float(v << 16); }
static __device__ __forceinline__ float bf_hi(u32 v) { return __uint_as_float(v & 0xffff0000u); }
static __device__ __forceinline__ u16 f2bf(float f) {
    u32 u = __float_as_uint(f);
    u32 r = u + 0x7fffu + ((u >> 16) & 1u);   // RNE; inputs finite
    return (u16)(r >> 16);
}
static __device__ __forceinline__ u32 pack2(float a, float b) {
    return ((u32)f2bf(b) << 16) | (u32)f2bf(a);
}

// ---------------------------------------------------------------------------
// f32 -> bf16 convert (row-major, packed pairs)
// ---------------------------------------------------------------------------
__global__ __launch_bounds__(256) void convert_k(const float* __restrict__ in,
                                                 u32* __restrict__ out2, int total4)
{
    for (int i = blockIdx.x * 256 + threadIdx.x; i < total4; i += gridDim.x * 256) {
        float4 v = reinterpret_cast<const float4*>(in)[i];
        out2[2 * i + 0] = pack2(v.x, v.y);
        out2[2 * i + 1] = pack2(v.z, v.w);
    }
}

// ---------------------------------------------------------------------------
// weight prep (all 4 mats in one launch): W (128x128 f32, row-major W[k][n])
// -> fragment-ordered bf16
// Wf[((kg*8+nb)*64 + l)*8 + j] = W[kg*32 + (l>>4)*8 + j][nb*16 + (l&15)]
// ---------------------------------------------------------------------------
__global__ __launch_bounds__(256) void wprep_k(const float* __restrict__ Wa,
                                               const float* __restrict__ Wb,
                                               const float* __restrict__ Wc,
                                               const float* __restrict__ Wd,
                                               u16* __restrict__ Wf)
{
    int g = blockIdx.x * 256 + threadIdx.x;   // 0..65535
    int which = g >> 14;
    int t = g & 16383;
    const float* W = which == 0 ? Wa : which == 1 ? Wb : which == 2 ? Wc : Wd;
    int j  = t & 7;
    int l  = (t >> 3) & 63;
    int nb = (t >> 9) & 7;
    int kg = (t >> 12) & 3;
    int k  = kg * 32 + (l >> 4) * 8 + j;
    int n  = nb * 16 + (l & 15);
    Wf[g] = f2bf(W[k * 128 + n]);
}

// ---------------------------------------------------------------------------
// Coarse bucket sort by dst>>7 (128 rows/bucket). NB <= 1024, N <= 131072.
// packed edge: (dst&127)<<17 | src   (src needs 17 bits)
// ---------------------------------------------------------------------------
__global__ __launch_bounds__(256) void bhist_k(const int* __restrict__ edst,
                                               int* __restrict__ gcount, int E, int NB)
{
    __shared__ int lh[1024];
    for (int i = threadIdx.x; i < 1024; i += 256) lh[i] = 0;
    __syncthreads();
    for (int e = blockIdx.x * 256 + threadIdx.x; e < E; e += gridDim.x * 256)
        atomicAdd(&lh[edst[e] >> 7], 1);
    __syncthreads();
    for (int b = threadIdx.x; b < NB; b += 256)
        if (lh[b]) atomicAdd(&gcount[b], lh[b]);
}

__global__ __launch_bounds__(1024) void bscan_k(const int* __restrict__ gcount,
                                                int* __restrict__ goffs,
                                                int* __restrict__ gcur, int NB)
{
    __shared__ int s[1024];
    int t = threadIdx.x;
    int v = (t < NB) ? gcount[t] : 0;
    s[t] = v; __syncthreads();
    for (int d = 1; d < 1024; d <<= 1) {
        int x = (t >= d) ? s[t - d] : 0;
        __syncthreads();
        s[t] += x;
        __syncthreads();
    }
    if (t < NB) { int o = s[t] - v; goffs[t] = o; gcur[t] = o; }
    if (t == NB - 1) goffs[NB] = s[t];
}

__global__ __launch_bounds__(256) void bfill_k(const int* __restrict__ esrc,
                                               const int* __restrict__ edst,
                                               int* __restrict__ gcur,
                                               u32* __restrict__ bpacked, int E, int NB)
{
    __shared__ int lh[1024];
    __shared__ int lbase[1024];
    int t = threadIdx.x;
    for (int i = t; i < 1024; i += 256) lh[i] = 0;
    __syncthreads();
    int per = (E + gridDim.x - 1) / gridDim.x;
    int lo = blockIdx.x * per;
    int hi = lo + per; if (hi > E) hi = E;
    for (int e = lo + t; e < hi; e += 256) atomicAdd(&lh[edst[e] >> 7], 1);
    __syncthreads();
    for (int b = t; b < NB; b += 256) {
        int c = lh[b];
        lbase[b] = c ? atomicAdd(&gcur[b], c) : 0;
    }
    __syncthreads();
    for (int i = t; i < 1024; i += 256) lh[i] = 0;   // reuse as local cursor
    __syncthreads();
    for (int e = lo + t; e < hi; e += 256) {
        int d = edst[e];
        int b = d >> 7;
        int idx = atomicAdd(&lh[b], 1);
        bpacked[lbase[b] + idx] = ((u32)(d & 127) << 17) | (u32)esrc[e];
    }
}

// ---------------------------------------------------------------------------
// fine counting sort within each bucket -> dst-sorted slots + per-row offs/deg
// ---------------------------------------------------------------------------
__global__ __launch_bounds__(256) void fsort_k(const u32* __restrict__ bpacked,
                                               const int* __restrict__ goffs,
                                               int* __restrict__ slots,
                                               int* __restrict__ offs,
                                               int* __restrict__ deg, int N)
{
    __shared__ int cnt[128];
    __shared__ int roff[128];
    int b = blockIdx.x, t = threadIdx.x;
    int start = goffs[b], end = goffs[b + 1];
    if (t < 128) cnt[t] = 0;
    __syncthreads();
    for (int e = start + t; e < end; e += 256)
        atomicAdd(&cnt[bpacked[e] >> 17], 1);
    __syncthreads();
    if (t == 0) {
        int acc = 0;
        for (int i = 0; i < 128; ++i) { roff[i] = acc; acc += cnt[i]; }
    }
    __syncthreads();
    int row0 = b * 128;
    if (t < 128 && row0 + t < N) {
        offs[row0 + t] = start + roff[t];
        deg[row0 + t]  = cnt[t];
    }
    if (t < 128) cnt[t] = 0;   // reuse as cursor
    __syncthreads();
    for (int e = start + t; e < end; e += 256) {
        u32 pk = bpacked[e];
        int local = (int)(pk >> 17);
        int idx = atomicAdd(&cnt[local], 1);
        slots[start + roff[local] + idx] = (int)(pk & 0x1FFFF);
    }
}

// ---------------------------------------------------------------------------
// FUSED layer: gather (-> LDS tile directly) + MFMA MLP + BN stats.
// MODE 0 (layer 1): input = raw bf16 x; output = bf16 h1 (hb_out).
// MODE 1 (layer 2): input = raw bf16 h1; BN of layer 1 is FOLDED into the
//   gather:  a.(h_row + sum h_s) + (deg+1).b   (BN is affine); output = f32
//   h2 (hf_out).
// Block = 256 thr = 4 waves, 64 rows. Wave w gathers rows w*16..+15 into the
// swizzled ta tile, then owns output cols w*32..+31 for the MLP.
// ---------------------------------------------------------------------------
template<int MODE>
__global__ __launch_bounds__(256) void fused_k(
    const u32* __restrict__ xin2,
    const int* __restrict__ offs, const int* __restrict__ deg,
    const int* __restrict__ slots,
    const float* __restrict__ stats_in, const float* __restrict__ g_in,
    const float* __restrict__ be_in,
    const u16* __restrict__ wfa, const float* __restrict__ ba,
    const u16* __restrict__ wfb, const float* __restrict__ bb,
    u16* __restrict__ hb_out, float* __restrict__ hf_out,
    float* __restrict__ stats_out, int N)
{
    __shared__ short ta[64 * 128];   // 16 KB input tile (bf16, swizzled)
    __shared__ short tc[64 * 128];   // 16 KB intermediate tile
    __shared__ float ssum[256];
    __shared__ float sc[128], sh[128];

    int t = threadIdx.x;
    int w = t >> 6, lane = t & 63;
    int row0 = blockIdx.x * 64;

    if (MODE == 1) {
        if (t < 128) {
            float invN = 1.0f / (float)N;
            float mean = stats_in[t] * invN;
            float var  = stats_in[128 + t] * invN - mean * mean;
            float s = g_in[t] * rsqrtf(var + 1e-5f);
            sc[t] = s;
            sh[t] = be_in[t] - mean * s;
        }
        __syncthreads();   // sc/sh visible to whole block before gather
    }
    ssum[t] = 0.0f;

    // prefetch W1 fragments for this wave's two 16-col blocks
    bf16x8 wf[2][4];
#pragma unroll
    for (int nr = 0; nr < 2; ++nr) {
        int nb = 2 * w + nr;
#pragma unroll
        for (int kg = 0; kg < 4; ++kg)
            wf[nr][kg] = *reinterpret_cast<const bf16x8*>(
                wfa + ((size_t)((kg * 8 + nb) * 64 + lane)) * 8);
    }

    // ---- gather phase: wave w fills rows w*16..+15 of ta ----
    for (int rq = 0; rq < 16; ++rq) {
        int r = w * 16 + rq;
        int row = row0 + r;
        int dst = (r * 128 + 2 * lane) ^ ((r & 7) << 3);  // even -> 4B aligned
        if (row < N) {
            u32 self = xin2[(size_t)row * 64 + lane];
            float ax0 = bf_lo(self), ay0 = bf_hi(self);
            float ax1 = 0.f, ay1 = 0.f;
            int start = offs[row];
            int dg = deg[row];
            for (int base = 0; base < dg; base += 64) {
                int rem = dg - base;
                int m = rem < 64 ? rem : 64;
                int slot = (lane < m) ? slots[start + base + lane] : 0;
                int j = 0;
                for (; j + 8 <= m; j += 8) {
                    int s0 = __shfl(slot, j + 0);
                    int s1 = __shfl(slot, j + 1);
                    int s2 = __shfl(slot, j + 2);
                    int s3 = __shfl(slot, j + 3);
                    int s4 = __shfl(slot, j + 4);
                    int s5 = __shfl(slot, j + 5);
                    int s6 = __shfl(slot, j + 6);
                    int s7 = __shfl(slot, j + 7);
                    u32 v0 = xin2[(size_t)s0 * 64 + lane];
                    u32 v1 = xin2[(size_t)s1 * 64 + lane];
                    u32 v2 = xin2[(size_t)s2 * 64 + lane];
                    u32 v3 = xin2[(size_t)s3 * 64 + lane];
                    u32 v4 = xin2[(size_t)s4 * 64 + lane];
                    u32 v5 = xin2[(size_t)s5 * 64 + lane];
                    u32 v6 = xin2[(size_t)s6 * 64 + lane];
                    u32 v7 = xin2[(size_t)s7 * 64 + lane];
                    ax0 += bf_lo(v0); ay0 += bf_hi(v0);
                    ax1 += bf_lo(v1); ay1 += bf_hi(v1);
                    ax0 += bf_lo(v2); ay0 += bf_hi(v2);
                    ax1 += bf_lo(v3); ay1 += bf_hi(v3);
                    ax0 += bf_lo(v4); ay0 += bf_hi(v4);
                    ax1 += bf_lo(v5); ay1 += bf_hi(v5);
                    ax0 += bf_lo(v6); ay0 += bf_hi(v6);
                    ax1 += bf_lo(v7); ay1 += bf_hi(v7);
                }
                for (; j < m; ++j) {
                    int s = __shfl(slot, j);
                    u32 v = xin2[(size_t)s * 64 + lane];
                    ax0 += bf_lo(v);
                    ay0 += bf_hi(v);
                }
            }
            float ax = ax0 + ax1, ay = ay0 + ay1;
            if (MODE == 1) {
                float d1 = (float)(dg + 1);
                ax = sc[2 * lane]     * ax + d1 * sh[2 * lane];
                ay = sc[2 * lane + 1] * ay + d1 * sh[2 * lane + 1];
            }
            *reinterpret_cast<u32*>(ta + dst) = pack2(ax, ay);
        } else {
            *reinterpret_cast<u32*>(ta + dst) = 0;
        }
    }
    __syncthreads();

    // ---- MLP phase (identical structure to round-5 mlp_mfma_k) ----
    int rr = lane & 15;    // row within 16-tile
    int kg8 = lane >> 4;   // k sub-group

    f32x4 acc[4][2];
#pragma unroll
    for (int mr = 0; mr < 4; ++mr)
#pragma unroll
        for (int nr = 0; nr < 2; ++nr)
            acc[mr][nr] = f32x4{0.f, 0.f, 0.f, 0.f};

#pragma unroll
    for (int mr = 0; mr < 4; ++mr) {
        int r = mr * 16 + rr;
        bf16x8 af[4];
#pragma unroll
        for (int kg = 0; kg < 4; ++kg) {
            int idx = (r * 128 + kg * 32 + kg8 * 8) ^ ((r & 7) << 3);
            af[kg] = *reinterpret_cast<const bf16x8*>(ta + idx);
        }
#pragma unroll
        for (int nr = 0; nr < 2; ++nr)
#pragma unroll
            for (int kg = 0; kg < 4; ++kg)
                acc[mr][nr] = __builtin_amdgcn_mfma_f32_16x16x32_bf16(
                    af[kg], wf[nr][kg], acc[mr][nr], 0, 0, 0);
    }

    // bias + relu -> tc (bf16, swizzled)
    int colb = w * 32;
    float b0 = ba[colb + rr];
    float b1 = ba[colb + 16 + rr];
#pragma unroll
    for (int mr = 0; mr < 4; ++mr)
#pragma unroll
        for (int nr = 0; nr < 2; ++nr) {
            float bb_ = nr ? b1 : b0;
            int col = colb + nr * 16 + rr;
#pragma unroll
            for (int reg = 0; reg < 4; ++reg) {
                int row = mr * 16 + kg8 * 4 + reg;
                float v = fmaxf(acc[mr][nr][reg] + bb_, 0.0f);
                tc[(row * 128 + col) ^ ((row & 7) << 3)] = (short)f2bf(v);
            }
        }

    // W2 fragments
#pragma unroll
    for (int nr = 0; nr < 2; ++nr) {
        int nb = 2 * w + nr;
#pragma unroll
        for (int kg = 0; kg < 4; ++kg)
            wf[nr][kg] = *reinterpret_cast<const bf16x8*>(
                wfb + ((size_t)((kg * 8 + nb) * 64 + lane)) * 8);
    }
    __syncthreads();

#pragma unroll
    for (int mr = 0; mr < 4; ++mr)
#pragma unroll
        for (int nr = 0; nr < 2; ++nr)
            acc[mr][nr] = f32x4{0.f, 0.f, 0.f, 0.f};

#pragma unroll
    for (int mr = 0; mr < 4; ++mr) {
        int r = mr * 16 + rr;
        bf16x8 af[4];
#pragma unroll
        for (int kg = 0; kg < 4; ++kg) {
            int idx = (r * 128 + kg * 32 + kg8 * 8) ^ ((r & 7) << 3);
            af[kg] = *reinterpret_cast<const bf16x8*>(tc + idx);
        }
#pragma unroll
        for (int nr = 0; nr < 2; ++nr)
#pragma unroll
            for (int kg = 0; kg < 4; ++kg)
                acc[mr][nr] = __builtin_amdgcn_mfma_f32_16x16x32_bf16(
                    af[kg], wf[nr][kg], acc[mr][nr], 0, 0, 0);
    }

    // bias + relu + store + BN stats
    float c0 = bb[colb + rr];
    float c1 = bb[colb + 16 + rr];
    float s0 = 0.f, q0 = 0.f, s1 = 0.f, q1 = 0.f;
#pragma unroll
    for (int mr = 0; mr < 4; ++mr) {
#pragma unroll
        for (int reg = 0; reg < 4; ++reg) {
            int row = row0 + mr * 16 + kg8 * 4 + reg;
            bool ok = row < N;
            float v0 = fmaxf(acc[mr][0][reg] + c0, 0.0f);
            float v1 = fmaxf(acc[mr][1][reg] + c1, 0.0f);
            if (ok) {
                if (MODE == 0) {
                    hb_out[(size_t)row * 128 + colb + rr]      = f2bf(v0);
                    hb_out[(size_t)row * 128 + colb + 16 + rr] = f2bf(v1);
                } else {
                    hf_out[(size_t)row * 128 + colb + rr]      = v0;
                    hf_out[(size_t)row * 128 + colb + 16 + rr] = v1;
                }
                s0 += v0; q0 += v0 * v0;
                s1 += v1; q1 += v1 * v1;
            }
        }
    }
    s0 += __shfl_xor(s0, 16); s0 += __shfl_xor(s0, 32);
    q0 += __shfl_xor(q0, 16); q0 += __shfl_xor(q0, 32);
    s1 += __shfl_xor(s1, 16); s1 += __shfl_xor(s1, 32);
    q1 += __shfl_xor(q1, 16); q1 += __shfl_xor(q1, 32);
    if (kg8 == 0) {
        atomicAdd(&ssum[colb + rr], s0);
        atomicAdd(&ssum[128 + colb + rr], q0);
        atomicAdd(&ssum[colb + 16 + rr], s1);
        atomicAdd(&ssum[128 + colb + 16 + rr], q1);
    }
    __syncthreads();
    atomicAdd(&stats_out[t], ssum[t]);
}

// ---------------------------------------------------------------------------
// final BN: in-place f32 on d_out
// ---------------------------------------------------------------------------
__global__ __launch_bounds__(256) void bn_apply_k(
    float* __restrict__ h, const float* __restrict__ stats,
    const float* __restrict__ gamma, const float* __restrict__ beta, int N)
{
    __shared__ float sc[128], sh[128];
    int t = threadIdx.x;
    if (t < 128) {
        float invN = 1.0f / (float)N;
        float mean = stats[t] * invN;
        float var  = stats[128 + t] * invN - mean * mean;
        float s = gamma[t] * rsqrtf(var + 1e-5f);
        sc[t] = s;
        sh[t] = beta[t] - mean * s;
    }
    __syncthreads();
    int total = N * 32;
    for (int i = blockIdx.x * 256 + t; i < total; i += gridDim.x * 256) {
        float4 v = reinterpret_cast<float4*>(h)[i];
        int c = (i & 31) * 4;
        v.x = v.x * sc[c + 0] + sh[c + 0];
        v.y = v.y * sc[c + 1] + sh[c + 1];
        v.z = v.z * sc[c + 2] + sh[c + 2];
        v.w = v.w * sc[c + 3] + sh[c + 3];
        reinterpret_cast<float4*>(h)[i] = v;
    }
}

// ---------------------------------------------------------------------------
extern "C" void kernel_launch(void* const* d_in, const int* in_sizes, int n_in,
                              void* d_out, int out_size, void* d_ws, size_t ws_size,
                              hipStream_t stream)
{
    const float* x   = (const float*)d_in[0];
    const int*   ei  = (const int*)d_in[1];
    const float* W1a = (const float*)d_in[2];
    const float* b1a = (const float*)d_in[3];
    const float* W1b = (const float*)d_in[4];
    const float* b1b = (const float*)d_in[5];
    const float* g1  = (const float*)d_in[6];
    const float* be1 = (const float*)d_in[7];
    const float* W2a = (const float*)d_in[8];
    const float* b2a = (const float*)d_in[9];
    const float* W2b = (const float*)d_in[10];
    const float* b2b = (const float*)d_in[11];
    const float* g2  = (const float*)d_in[12];
    const float* be2 = (const float*)d_in[13];

    const int N = in_sizes[0] / 128;
    const int E = in_sizes[1] / 2;
    const int* esrc = ei;
    const int* edst = ei + E;
    const int NB = (N + 127) >> 7;   // 128-row buckets; requires N <= 131072

    // ---- workspace carve (bpacked aliases h1: dead before fused L1) ----
    char* p = (char*)d_ws;
    const size_t featb = (size_t)N * 128 * sizeof(u16);     // 25.6 MB
    u16* h1 = (u16*)p;            p += featb;               // layer-1 bf16 output
    u16* xb = (u16*)p;            p += featb;               // bf16 input features
    u16* wf = (u16*)p;            p += 4 * 16384 * sizeof(u16);
    int* slots = (int*)p;         p += (size_t)E * sizeof(int);
    int* deg   = (int*)p;         p += (size_t)N * sizeof(int);
    int* offs  = (int*)p;         p += (size_t)N * sizeof(int);
    int* gcount = (int*)p;        p += 1024 * sizeof(int);
    int* goffs  = (int*)p;        p += 1032 * sizeof(int);
    int* gcur   = (int*)p;        p += 1024 * sizeof(int);
    float* stats = (float*)p;     p += 512 * sizeof(float);
    u32* bpacked = (u32*)h1;      // alias (E*4 = 6.4MB <= featb)

    u16* wf1a = wf;
    u16* wf1b = wf + 16384;
    u16* wf2a = wf + 32768;
    u16* wf2b = wf + 49152;
    float* stats1 = stats;
    float* stats2 = stats + 256;

    float* h = (float*)d_out;
    const int mblocks = (N + 63) / 64;

    // ---- one-time prep: bucket sort -> fine sort -> CSR; bf16 conversions ----
    hipMemsetAsync(gcount, 0, 1024 * sizeof(int), stream);
    bhist_k<<<256, 256, 0, stream>>>(edst, gcount, E, NB);
    bscan_k<<<1, 1024, 0, stream>>>(gcount, goffs, gcur, NB);
    bfill_k<<<256, 256, 0, stream>>>(esrc, edst, gcur, bpacked, E, NB);
    fsort_k<<<NB, 256, 0, stream>>>(bpacked, goffs, slots, offs, deg, N);
    convert_k<<<2048, 256, 0, stream>>>(x, (u32*)xb, N * 32);
    wprep_k<<<256, 256, 0, stream>>>(W1a, W1b, W2a, W2b, wf);
    hipMemsetAsync(stats, 0, 512 * sizeof(float), stream);

    // ---- layer 1 (fused gather+MLP): xb -> h1 (bf16) + stats1 ----
    fused_k<0><<<mblocks, 256, 0, stream>>>(
        (const u32*)xb, offs, deg, slots,
        (const float*)nullptr, (const float*)nullptr, (const float*)nullptr,
        wf1a, b1a, wf1b, b1b, h1, (float*)nullptr, stats1, N);

    // ---- layer 2 (fused, BN1 folded into gather): h1 -> h (f32) + stats2 ----
    fused_k<1><<<mblocks, 256, 0, stream>>>(
        (const u32*)h1, offs, deg, slots,
        stats1, g1, be1,
        wf2a, b2a, wf2b, b2b, (u16*)nullptr, h, stats2, N);

    // ---- final BN in place on d_out ----
    bn_apply_k<<<2048, 256, 0, stream>>>(h, stats2, g2, be2, N);
}

// Round 7
// 355.005 us; speedup vs baseline: 1.1439x; 1.1439x over previous
//
#include <hip/hip_runtime.h>
#include <hip/hip_bf16.h>

typedef unsigned int u32;
typedef unsigned short u16;
typedef short bf16x8 __attribute__((ext_vector_type(8)));
typedef float f32x4 __attribute__((ext_vector_type(4)));

static __device__ __forceinline__ float bf_lo(u32 v) { return __uint_as_float(v << 16); }
static __device__ __forceinline__ float bf_hi(u32 v) { return __uint_as_float(v & 0xffff0000u); }
static __device__ __forceinline__ u16 f2bf(float f) {
    u32 u = __float_as_uint(f);
    u32 r = u + 0x7fffu + ((u >> 16) & 1u);   // RNE; inputs finite
    return (u16)(r >> 16);
}
static __device__ __forceinline__ u32 pack2(float a, float b) {
    return ((u32)f2bf(b) << 16) | (u32)f2bf(a);
}

// ---------------------------------------------------------------------------
// f32 -> bf16 convert (row-major, packed pairs)
// ---------------------------------------------------------------------------
__global__ __launch_bounds__(256) void convert_k(const float* __restrict__ in,
                                                 u32* __restrict__ out2, int total4)
{
    for (int i = blockIdx.x * 256 + threadIdx.x; i < total4; i += gridDim.x * 256) {
        float4 v = reinterpret_cast<const float4*>(in)[i];
        out2[2 * i + 0] = pack2(v.x, v.y);
        out2[2 * i + 1] = pack2(v.z, v.w);
    }
}

// ---------------------------------------------------------------------------
// weight prep (all 4 mats in one launch): W (128x128 f32, row-major W[k][n])
// -> fragment-ordered bf16
// Wf[((kg*8+nb)*64 + l)*8 + j] = W[kg*32 + (l>>4)*8 + j][nb*16 + (l&15)]
// ---------------------------------------------------------------------------
__global__ __launch_bounds__(256) void wprep_k(const float* __restrict__ Wa,
                                               const float* __restrict__ Wb,
                                               const float* __restrict__ Wc,
                                               const float* __restrict__ Wd,
                                               u16* __restrict__ Wf)
{
    int g = blockIdx.x * 256 + threadIdx.x;   // 0..65535
    int which = g >> 14;
    int t = g & 16383;
    const float* W = which == 0 ? Wa : which == 1 ? Wb : which == 2 ? Wc : Wd;
    int j  = t & 7;
    int l  = (t >> 3) & 63;
    int nb = (t >> 9) & 7;
    int kg = (t >> 12) & 3;
    int k  = kg * 32 + (l >> 4) * 8 + j;
    int n  = nb * 16 + (l & 15);
    Wf[g] = f2bf(W[k * 128 + n]);
}

// ---------------------------------------------------------------------------
// Coarse bucket sort by dst>>7 (128 rows/bucket). NB <= 1024, N <= 131072.
// packed edge: (dst&127)<<17 | src   (src needs 17 bits)
// ---------------------------------------------------------------------------
__global__ __launch_bounds__(256) void bhist_k(const int* __restrict__ edst,
                                               int* __restrict__ gcount, int E, int NB)
{
    __shared__ int lh[1024];
    for (int i = threadIdx.x; i < 1024; i += 256) lh[i] = 0;
    __syncthreads();
    for (int e = blockIdx.x * 256 + threadIdx.x; e < E; e += gridDim.x * 256)
        atomicAdd(&lh[edst[e] >> 7], 1);
    __syncthreads();
    for (int b = threadIdx.x; b < NB; b += 256)
        if (lh[b]) atomicAdd(&gcount[b], lh[b]);
}

__global__ __launch_bounds__(1024) void bscan_k(const int* __restrict__ gcount,
                                                int* __restrict__ goffs,
                                                int* __restrict__ gcur, int NB)
{
    __shared__ int s[1024];
    int t = threadIdx.x;
    int v = (t < NB) ? gcount[t] : 0;
    s[t] = v; __syncthreads();
    for (int d = 1; d < 1024; d <<= 1) {
        int x = (t >= d) ? s[t - d] : 0;
        __syncthreads();
        s[t] += x;
        __syncthreads();
    }
    if (t < NB) { int o = s[t] - v; goffs[t] = o; gcur[t] = o; }
    if (t == NB - 1) goffs[NB] = s[t];
}

__global__ __launch_bounds__(256) void bfill_k(const int* __restrict__ esrc,
                                               const int* __restrict__ edst,
                                               int* __restrict__ gcur,
                                               u32* __restrict__ bpacked, int E, int NB)
{
    __shared__ int lh[1024];
    __shared__ int lbase[1024];
    int t = threadIdx.x;
    for (int i = t; i < 1024; i += 256) lh[i] = 0;
    __syncthreads();
    int per = (E + gridDim.x - 1) / gridDim.x;
    int lo = blockIdx.x * per;
    int hi = lo + per; if (hi > E) hi = E;
    for (int e = lo + t; e < hi; e += 256) atomicAdd(&lh[edst[e] >> 7], 1);
    __syncthreads();
    for (int b = t; b < NB; b += 256) {
        int c = lh[b];
        lbase[b] = c ? atomicAdd(&gcur[b], c) : 0;
    }
    __syncthreads();
    for (int i = t; i < 1024; i += 256) lh[i] = 0;   // reuse as local cursor
    __syncthreads();
    for (int e = lo + t; e < hi; e += 256) {
        int d = edst[e];
        int b = d >> 7;
        int idx = atomicAdd(&lh[b], 1);
        bpacked[lbase[b] + idx] = ((u32)(d & 127) << 17) | (u32)esrc[e];
    }
}

// ---------------------------------------------------------------------------
// fine counting sort within each bucket -> dst-sorted slots + per-row offs/deg
// ---------------------------------------------------------------------------
__global__ __launch_bounds__(256) void fsort_k(const u32* __restrict__ bpacked,
                                               const int* __restrict__ goffs,
                                               int* __restrict__ slots,
                                               int* __restrict__ offs,
                                               int* __restrict__ deg, int N)
{
    __shared__ int cnt[128];
    __shared__ int roff[128];
    int b = blockIdx.x, t = threadIdx.x;
    int start = goffs[b], end = goffs[b + 1];
    if (t < 128) cnt[t] = 0;
    __syncthreads();
    for (int e = start + t; e < end; e += 256)
        atomicAdd(&cnt[bpacked[e] >> 17], 1);
    __syncthreads();
    if (t == 0) {
        int acc = 0;
        for (int i = 0; i < 128; ++i) { roff[i] = acc; acc += cnt[i]; }
    }
    __syncthreads();
    int row0 = b * 128;
    if (t < 128 && row0 + t < N) {
        offs[row0 + t] = start + roff[t];
        deg[row0 + t]  = cnt[t];
    }
    if (t < 128) cnt[t] = 0;   // reuse as cursor
    __syncthreads();
    for (int e = start + t; e < end; e += 256) {
        u32 pk = bpacked[e];
        int local = (int)(pk >> 17);
        int idx = atomicAdd(&cnt[local], 1);
        slots[start + roff[local] + idx] = (int)(pk & 0x1FFFF);
    }
}

// ---------------------------------------------------------------------------
// gather-aggregate: one wave per row; lane owns 2 cols (packed bf16 pair).
// 8x unrolled edge loop -> ~8 independent row loads in flight per wave.
// MODE 0: xa[row] = bf16( x[row] + sum_nbr x[s] )
// MODE 1: BN of previous layer folded in (BN affine):
//         xa[row] = bf16( sc.(h[row]+sum h[s]) + (deg+1).sh )
// ---------------------------------------------------------------------------
template<int MODE>
__global__ __launch_bounds__(256) void gather_k(const u32* __restrict__ xb2,
                                                const int* __restrict__ offs,
                                                const int* __restrict__ deg,
                                                const int* __restrict__ slots,
                                                const float* __restrict__ stats_in,
                                                const float* __restrict__ g_in,
                                                const float* __restrict__ be_in,
                                                u32* __restrict__ xa2, int N)
{
    __shared__ float sc[128], sh[128];
    int t = threadIdx.x;
    if (MODE == 1) {
        if (t < 128) {
            float invN = 1.0f / (float)N;
            float mean = stats_in[t] * invN;
            float var  = stats_in[128 + t] * invN - mean * mean;
            float s = g_in[t] * rsqrtf(var + 1e-5f);
            sc[t] = s;
            sh[t] = be_in[t] - mean * s;
        }
        __syncthreads();
    }

    int row = blockIdx.x * 4 + (t >> 6);
    if (row >= N) return;
    int lane = t & 63;

    u32 self = xb2[(size_t)row * 64 + lane];
    float ax0 = bf_lo(self), ay0 = bf_hi(self);
    float ax1 = 0.f, ay1 = 0.f;

    int start = offs[row];
    int dg = deg[row];
    for (int base = 0; base < dg; base += 64) {
        int rem = dg - base;
        int m = rem < 64 ? rem : 64;
        int slot = (lane < m) ? slots[start + base + lane] : 0;
        int j = 0;
        for (; j + 8 <= m; j += 8) {
            int s0 = __shfl(slot, j + 0);
            int s1 = __shfl(slot, j + 1);
            int s2 = __shfl(slot, j + 2);
            int s3 = __shfl(slot, j + 3);
            int s4 = __shfl(slot, j + 4);
            int s5 = __shfl(slot, j + 5);
            int s6 = __shfl(slot, j + 6);
            int s7 = __shfl(slot, j + 7);
            u32 v0 = xb2[(size_t)s0 * 64 + lane];
            u32 v1 = xb2[(size_t)s1 * 64 + lane];
            u32 v2 = xb2[(size_t)s2 * 64 + lane];
            u32 v3 = xb2[(size_t)s3 * 64 + lane];
            u32 v4 = xb2[(size_t)s4 * 64 + lane];
            u32 v5 = xb2[(size_t)s5 * 64 + lane];
            u32 v6 = xb2[(size_t)s6 * 64 + lane];
            u32 v7 = xb2[(size_t)s7 * 64 + lane];
            ax0 += bf_lo(v0); ay0 += bf_hi(v0);
            ax1 += bf_lo(v1); ay1 += bf_hi(v1);
            ax0 += bf_lo(v2); ay0 += bf_hi(v2);
            ax1 += bf_lo(v3); ay1 += bf_hi(v3);
            ax0 += bf_lo(v4); ay0 += bf_hi(v4);
            ax1 += bf_lo(v5); ay1 += bf_hi(v5);
            ax0 += bf_lo(v6); ay0 += bf_hi(v6);
            ax1 += bf_lo(v7); ay1 += bf_hi(v7);
        }
        for (; j < m; ++j) {
            int s = __shfl(slot, j);
            u32 v = xb2[(size_t)s * 64 + lane];
            ax0 += bf_lo(v);
            ay0 += bf_hi(v);
        }
    }
    float ax = ax0 + ax1, ay = ay0 + ay1;
    if (MODE == 1) {
        float d1 = (float)(dg + 1);
        ax = sc[2 * lane]     * ax + d1 * sh[2 * lane];
        ay = sc[2 * lane + 1] * ay + d1 * sh[2 * lane + 1];
    }
    xa2[(size_t)row * 64 + lane] = pack2(ax, ay);
}

// ---------------------------------------------------------------------------
// fused MFMA MLP: h = relu(relu(XA@Wa + ba)@Wb + bb), + per-col sum/sumsq.
// Block = 256 thr = 4 waves, 64 rows x 128 cols; wave w owns cols w*32..+31.
// SINGLE ta tile reused for the intermediate (extra barrier) -> LDS ~17.4KB
// -> 8 blocks/CU (was 2 tiles/33.8KB/4 blocks, occupancy 29%).
// MODE 0: store bf16 h1.  MODE 1: store f32 h2.
// ---------------------------------------------------------------------------
template<int MODE>
__global__ __launch_bounds__(256) void mlp_mfma_k(
    const u16* __restrict__ xa,
    const u16* __restrict__ wfa, const float* __restrict__ ba,
    const u16* __restrict__ wfb, const float* __restrict__ bb,
    u16* __restrict__ hb_out, float* __restrict__ hf_out,
    float* __restrict__ stats, int N)
{
    __shared__ short ta[64 * 128];   // 16 KB tile (bf16, swizzled), reused
    __shared__ float ssum[256];

    int t = threadIdx.x;
    int w = t >> 6, l = t & 63;
    int row0 = blockIdx.x * 64;

    // stage XA tile (swizzled)
    for (int c = t; c < 1024; c += 256) {
        int r = c >> 4, ci = c & 15;
        int dst = (r * 128 + ci * 8) ^ ((r & 7) << 3);
        f32x4 v;
        if (row0 + r < N)
            v = *reinterpret_cast<const f32x4*>(xa + ((size_t)(row0 + r) * 128 + ci * 8));
        else
            v = f32x4{0.f, 0.f, 0.f, 0.f};
        *reinterpret_cast<f32x4*>(ta + dst) = v;
    }
    ssum[t] = 0.0f;

    // W1 fragments for this wave's two 16-col blocks
    bf16x8 wf[2][4];
#pragma unroll
    for (int nr = 0; nr < 2; ++nr) {
        int nb = 2 * w + nr;
#pragma unroll
        for (int kg = 0; kg < 4; ++kg)
            wf[nr][kg] = *reinterpret_cast<const bf16x8*>(
                wfa + ((size_t)((kg * 8 + nb) * 64 + l)) * 8);
    }
    __syncthreads();

    int rr = l & 15;       // row within 16-tile
    int kg8 = l >> 4;      // k sub-group

    f32x4 acc[4][2];
#pragma unroll
    for (int mr = 0; mr < 4; ++mr)
#pragma unroll
        for (int nr = 0; nr < 2; ++nr)
            acc[mr][nr] = f32x4{0.f, 0.f, 0.f, 0.f};

#pragma unroll
    for (int mr = 0; mr < 4; ++mr) {
        int r = mr * 16 + rr;
        bf16x8 af[4];
#pragma unroll
        for (int kg = 0; kg < 4; ++kg) {
            int idx = (r * 128 + kg * 32 + kg8 * 8) ^ ((r & 7) << 3);
            af[kg] = *reinterpret_cast<const bf16x8*>(ta + idx);
        }
#pragma unroll
        for (int nr = 0; nr < 2; ++nr)
#pragma unroll
            for (int kg = 0; kg < 4; ++kg)
                acc[mr][nr] = __builtin_amdgcn_mfma_f32_16x16x32_bf16(
                    af[kg], wf[nr][kg], acc[mr][nr], 0, 0, 0);
    }
    __syncthreads();   // all GEMM1 reads of ta complete

    // bias + relu -> back into ta (bf16, swizzled)
    int colb = w * 32;
    float b0 = ba[colb + rr];
    float b1 = ba[colb + 16 + rr];
#pragma unroll
    for (int mr = 0; mr < 4; ++mr)
#pragma unroll
        for (int nr = 0; nr < 2; ++nr) {
            float bb_ = nr ? b1 : b0;
            int col = colb + nr * 16 + rr;
#pragma unroll
            for (int reg = 0; reg < 4; ++reg) {
                int row = mr * 16 + kg8 * 4 + reg;
                float v = fmaxf(acc[mr][nr][reg] + bb_, 0.0f);
                ta[(row * 128 + col) ^ ((row & 7) << 3)] = (short)f2bf(v);
            }
        }

    // W2 fragments
#pragma unroll
    for (int nr = 0; nr < 2; ++nr) {
        int nb = 2 * w + nr;
#pragma unroll
        for (int kg = 0; kg < 4; ++kg)
            wf[nr][kg] = *reinterpret_cast<const bf16x8*>(
                wfb + ((size_t)((kg * 8 + nb) * 64 + l)) * 8);
    }
    __syncthreads();   // intermediate tile fully written

#pragma unroll
    for (int mr = 0; mr < 4; ++mr)
#pragma unroll
        for (int nr = 0; nr < 2; ++nr)
            acc[mr][nr] = f32x4{0.f, 0.f, 0.f, 0.f};

#pragma unroll
    for (int mr = 0; mr < 4; ++mr) {
        int r = mr * 16 + rr;
        bf16x8 af[4];
#pragma unroll
        for (int kg = 0; kg < 4; ++kg) {
            int idx = (r * 128 + kg * 32 + kg8 * 8) ^ ((r & 7) << 3);
            af[kg] = *reinterpret_cast<const bf16x8*>(ta + idx);
        }
#pragma unroll
        for (int nr = 0; nr < 2; ++nr)
#pragma unroll
            for (int kg = 0; kg < 4; ++kg)
                acc[mr][nr] = __builtin_amdgcn_mfma_f32_16x16x32_bf16(
                    af[kg], wf[nr][kg], acc[mr][nr], 0, 0, 0);
    }

    // bias + relu + store + BN stats
    float c0 = bb[colb + rr];
    float c1 = bb[colb + 16 + rr];
    float s0 = 0.f, q0 = 0.f, s1 = 0.f, q1 = 0.f;
#pragma unroll
    for (int mr = 0; mr < 4; ++mr) {
#pragma unroll
        for (int reg = 0; reg < 4; ++reg) {
            int row = row0 + mr * 16 + kg8 * 4 + reg;
            bool ok = row < N;
            float v0 = fmaxf(acc[mr][0][reg] + c0, 0.0f);
            float v1 = fmaxf(acc[mr][1][reg] + c1, 0.0f);
            if (ok) {
                if (MODE == 0) {
                    hb_out[(size_t)row * 128 + colb + rr]      = f2bf(v0);
                    hb_out[(size_t)row * 128 + colb + 16 + rr] = f2bf(v1);
                } else {
                    hf_out[(size_t)row * 128 + colb + rr]      = v0;
                    hf_out[(size_t)row * 128 + colb + 16 + rr] = v1;
                }
                s0 += v0; q0 += v0 * v0;
                s1 += v1; q1 += v1 * v1;
            }
        }
    }
    s0 += __shfl_xor(s0, 16); s0 += __shfl_xor(s0, 32);
    q0 += __shfl_xor(q0, 16); q0 += __shfl_xor(q0, 32);
    s1 += __shfl_xor(s1, 16); s1 += __shfl_xor(s1, 32);
    q1 += __shfl_xor(q1, 16); q1 += __shfl_xor(q1, 32);
    if (kg8 == 0) {
        atomicAdd(&ssum[colb + rr], s0);
        atomicAdd(&ssum[128 + colb + rr], q0);
        atomicAdd(&ssum[colb + 16 + rr], s1);
        atomicAdd(&ssum[128 + colb + 16 + rr], q1);
    }
    __syncthreads();
    atomicAdd(&stats[t], ssum[t]);
}

// ---------------------------------------------------------------------------
// final BN: in-place f32 on d_out
// ---------------------------------------------------------------------------
__global__ __launch_bounds__(256) void bn_apply_k(
    float* __restrict__ h, const float* __restrict__ stats,
    const float* __restrict__ gamma, const float* __restrict__ beta, int N)
{
    __shared__ float sc[128], sh[128];
    int t = threadIdx.x;
    if (t < 128) {
        float invN = 1.0f / (float)N;
        float mean = stats[t] * invN;
        float var  = stats[128 + t] * invN - mean * mean;
        float s = gamma[t] * rsqrtf(var + 1e-5f);
        sc[t] = s;
        sh[t] = beta[t] - mean * s;
    }
    __syncthreads();
    int total = N * 32;
    for (int i = blockIdx.x * 256 + t; i < total; i += gridDim.x * 256) {
        float4 v = reinterpret_cast<float4*>(h)[i];
        int c = (i & 31) * 4;
        v.x = v.x * sc[c + 0] + sh[c + 0];
        v.y = v.y * sc[c + 1] + sh[c + 1];
        v.z = v.z * sc[c + 2] + sh[c + 2];
        v.w = v.w * sc[c + 3] + sh[c + 3];
        reinterpret_cast<float4*>(h)[i] = v;
    }
}

// ---------------------------------------------------------------------------
extern "C" void kernel_launch(void* const* d_in, const int* in_sizes, int n_in,
                              void* d_out, int out_size, void* d_ws, size_t ws_size,
                              hipStream_t stream)
{
    const float* x   = (const float*)d_in[0];
    const int*   ei  = (const int*)d_in[1];
    const float* W1a = (const float*)d_in[2];
    const float* b1a = (const float*)d_in[3];
    const float* W1b = (const float*)d_in[4];
    const float* b1b = (const float*)d_in[5];
    const float* g1  = (const float*)d_in[6];
    const float* be1 = (const float*)d_in[7];
    const float* W2a = (const float*)d_in[8];
    const float* b2a = (const float*)d_in[9];
    const float* W2b = (const float*)d_in[10];
    const float* b2b = (const float*)d_in[11];
    const float* g2  = (const float*)d_in[12];
    const float* be2 = (const float*)d_in[13];

    const int N = in_sizes[0] / 128;
    const int E = in_sizes[1] / 2;
    const int* esrc = ei;
    const int* edst = ei + E;
    const int NB = (N + 127) >> 7;   // 128-row buckets; requires N <= 131072

    // ---- workspace carve ----
    char* p = (char*)d_ws;
    const size_t featb = (size_t)N * 128 * sizeof(u16);     // 25.6 MB
    u16* xa = (u16*)p;            p += featb;               // gather output
    u16* h1 = (u16*)p;            p += featb;               // layer-1 bf16 output
    u16* xb = (u16*)p;            p += featb;               // bf16 input features
    u16* wf = (u16*)p;            p += 4 * 16384 * sizeof(u16);
    int* slots = (int*)p;         p += (size_t)E * sizeof(int);
    int* deg   = (int*)p;         p += (size_t)N * sizeof(int);
    int* offs  = (int*)p;         p += (size_t)N * sizeof(int);
    int* gcount = (int*)p;        p += 1024 * sizeof(int);
    int* goffs  = (int*)p;        p += 1032 * sizeof(int);
    int* gcur   = (int*)p;        p += 1024 * sizeof(int);
    float* stats = (float*)p;     p += 512 * sizeof(float);
    u32* bpacked = (u32*)xa;      // alias (E*4 = 6.4MB <= featb), dead early

    u16* wf1a = wf;
    u16* wf1b = wf + 16384;
    u16* wf2a = wf + 32768;
    u16* wf2b = wf + 49152;
    float* stats1 = stats;
    float* stats2 = stats + 256;

    float* h = (float*)d_out;
    const int mblocks = (N + 63) / 64;
    const int gblocks = (N + 3) / 4;

    // ---- one-time prep: bucket sort -> fine sort -> CSR; bf16 conversions ----
    hipMemsetAsync(gcount, 0, 1024 * sizeof(int), stream);
    bhist_k<<<256, 256, 0, stream>>>(edst, gcount, E, NB);
    bscan_k<<<1, 1024, 0, stream>>>(gcount, goffs, gcur, NB);
    bfill_k<<<256, 256, 0, stream>>>(esrc, edst, gcur, bpacked, E, NB);
    fsort_k<<<NB, 256, 0, stream>>>(bpacked, goffs, slots, offs, deg, N);
    convert_k<<<2048, 256, 0, stream>>>(x, (u32*)xb, N * 32);
    wprep_k<<<256, 256, 0, stream>>>(W1a, W1b, W2a, W2b, wf);
    hipMemsetAsync(stats, 0, 512 * sizeof(float), stream);

    // ---- layer 1: gather -> MLP (bf16 h1 + stats1) ----
    gather_k<0><<<gblocks, 256, 0, stream>>>((const u32*)xb, offs, deg, slots,
                                             nullptr, nullptr, nullptr, (u32*)xa, N);
    mlp_mfma_k<0><<<mblocks, 256, 0, stream>>>(xa, wf1a, b1a, wf1b, b1b,
                                               h1, (float*)nullptr, stats1, N);

    // ---- layer 2: gather (BN1 folded) -> MLP (f32 h + stats2) ----
    gather_k<1><<<gblocks, 256, 0, stream>>>((const u32*)h1, offs, deg, slots,
                                             stats1, g1, be1, (u32*)xa, N);
    mlp_mfma_k<1><<<mblocks, 256, 0, stream>>>(xa, wf2a, b2a, wf2b, b2b,
                                               (u16*)nullptr, h, stats2, N);

    // ---- final BN in place on d_out ----
    bn_apply_k<<<2048, 256, 0, stream>>>(h, stats2, g2, be2, N);
}

// Round 8
// 299.175 us; speedup vs baseline: 1.3574x; 1.1866x over previous
//
#include <hip/hip_runtime.h>
#include <hip/hip_bf16.h>

typedef unsigned int u32;
typedef unsigned short u16;
typedef short bf16x8 __attribute__((ext_vector_type(8)));
typedef float f32x4 __attribute__((ext_vector_type(4)));

static __device__ __forceinline__ float bf_lo(u32 v) { return __uint_as_float(v << 16); }
static __device__ __forceinline__ float bf_hi(u32 v) { return __uint_as_float(v & 0xffff0000u); }
static __device__ __forceinline__ u16 f2bf(float f) {
    u32 u = __float_as_uint(f);
    u32 r = u + 0x7fffu + ((u >> 16) & 1u);   // RNE; inputs finite
    return (u16)(r >> 16);
}
static __device__ __forceinline__ u32 pack2(float a, float b) {
    return ((u32)f2bf(b) << 16) | (u32)f2bf(a);
}

// ---------------------------------------------------------------------------
// f32 -> bf16 convert (row-major, packed pairs)
// ---------------------------------------------------------------------------
__global__ __launch_bounds__(256) void convert_k(const float* __restrict__ in,
                                                 u32* __restrict__ out2, int total4)
{
    for (int i = blockIdx.x * 256 + threadIdx.x; i < total4; i += gridDim.x * 256) {
        float4 v = reinterpret_cast<const float4*>(in)[i];
        out2[2 * i + 0] = pack2(v.x, v.y);
        out2[2 * i + 1] = pack2(v.z, v.w);
    }
}

// ---------------------------------------------------------------------------
// weight prep (all 4 mats in one launch): W (128x128 f32, row-major W[k][n])
// -> fragment-ordered bf16
// Wf[((kg*8+nb)*64 + l)*8 + j] = W[kg*32 + (l>>4)*8 + j][nb*16 + (l&15)]
// ---------------------------------------------------------------------------
__global__ __launch_bounds__(256) void wprep_k(const float* __restrict__ Wa,
                                               const float* __restrict__ Wb,
                                               const float* __restrict__ Wc,
                                               const float* __restrict__ Wd,
                                               u16* __restrict__ Wf)
{
    int g = blockIdx.x * 256 + threadIdx.x;   // 0..65535
    int which = g >> 14;
    int t = g & 16383;
    const float* W = which == 0 ? Wa : which == 1 ? Wb : which == 2 ? Wc : Wd;
    int j  = t & 7;
    int l  = (t >> 3) & 63;
    int nb = (t >> 9) & 7;
    int kg = (t >> 12) & 3;
    int k  = kg * 32 + (l >> 4) * 8 + j;
    int n  = nb * 16 + (l & 15);
    Wf[g] = f2bf(W[k * 128 + n]);
}

// ---------------------------------------------------------------------------
// Coarse bucket sort by dst>>7 (128 rows/bucket). NB <= 1024, N <= 131072.
// packed edge: (dst&127)<<17 | src   (src needs 17 bits)
// ---------------------------------------------------------------------------
__global__ __launch_bounds__(256) void bhist_k(const int* __restrict__ edst,
                                               int* __restrict__ gcount, int E, int NB)
{
    __shared__ int lh[1024];
    for (int i = threadIdx.x; i < 1024; i += 256) lh[i] = 0;
    __syncthreads();
    for (int e = blockIdx.x * 256 + threadIdx.x; e < E; e += gridDim.x * 256)
        atomicAdd(&lh[edst[e] >> 7], 1);
    __syncthreads();
    for (int b = threadIdx.x; b < NB; b += 256)
        if (lh[b]) atomicAdd(&gcount[b], lh[b]);
}

__global__ __launch_bounds__(1024) void bscan_k(const int* __restrict__ gcount,
                                                int* __restrict__ goffs,
                                                int* __restrict__ gcur, int NB)
{
    __shared__ int s[1024];
    int t = threadIdx.x;
    int v = (t < NB) ? gcount[t] : 0;
    s[t] = v; __syncthreads();
    for (int d = 1; d < 1024; d <<= 1) {
        int x = (t >= d) ? s[t - d] : 0;
        __syncthreads();
        s[t] += x;
        __syncthreads();
    }
    if (t < NB) { int o = s[t] - v; goffs[t] = o; gcur[t] = o; }
    if (t == NB - 1) goffs[NB] = s[t];
}

__global__ __launch_bounds__(256) void bfill_k(const int* __restrict__ esrc,
                                               const int* __restrict__ edst,
                                               int* __restrict__ gcur,
                                               u32* __restrict__ bpacked, int E, int NB)
{
    __shared__ int lh[1024];
    __shared__ int lbase[1024];
    int t = threadIdx.x;
    for (int i = t; i < 1024; i += 256) lh[i] = 0;
    __syncthreads();
    int per = (E + gridDim.x - 1) / gridDim.x;
    int lo = blockIdx.x * per;
    int hi = lo + per; if (hi > E) hi = E;
    for (int e = lo + t; e < hi; e += 256) atomicAdd(&lh[edst[e] >> 7], 1);
    __syncthreads();
    for (int b = t; b < NB; b += 256) {
        int c = lh[b];
        lbase[b] = c ? atomicAdd(&gcur[b], c) : 0;
    }
    __syncthreads();
    for (int i = t; i < 1024; i += 256) lh[i] = 0;   // reuse as local cursor
    __syncthreads();
    for (int e = lo + t; e < hi; e += 256) {
        int d = edst[e];
        int b = d >> 7;
        int idx = atomicAdd(&lh[b], 1);
        bpacked[lbase[b] + idx] = ((u32)(d & 127) << 17) | (u32)esrc[e];
    }
}

// ---------------------------------------------------------------------------
// fine counting sort within each bucket -> dst-sorted slots + per-row offs/deg
// ---------------------------------------------------------------------------
__global__ __launch_bounds__(256) void fsort_k(const u32* __restrict__ bpacked,
                                               const int* __restrict__ goffs,
                                               int* __restrict__ slots,
                                               int* __restrict__ offs,
                                               int* __restrict__ deg, int N)
{
    __shared__ int cnt[128];
    __shared__ int roff[128];
    int b = blockIdx.x, t = threadIdx.x;
    int start = goffs[b], end = goffs[b + 1];
    if (t < 128) cnt[t] = 0;
    __syncthreads();
    for (int e = start + t; e < end; e += 256)
        atomicAdd(&cnt[bpacked[e] >> 17], 1);
    __syncthreads();
    if (t == 0) {
        int acc = 0;
        for (int i = 0; i < 128; ++i) { roff[i] = acc; acc += cnt[i]; }
    }
    __syncthreads();
    int row0 = b * 128;
    if (t < 128 && row0 + t < N) {
        offs[row0 + t] = start + roff[t];
        deg[row0 + t]  = cnt[t];
    }
    if (t < 128) cnt[t] = 0;   // reuse as cursor
    __syncthreads();
    for (int e = start + t; e < end; e += 256) {
        u32 pk = bpacked[e];
        int local = (int)(pk >> 17);
        int idx = atomicAdd(&cnt[local], 1);
        slots[start + roff[local] + idx] = (int)(pk & 0x1FFFF);
    }
}

// ---------------------------------------------------------------------------
// gather-aggregate: one wave per row; lane owns 2 cols (packed bf16 pair).
// 8x unrolled edge loop -> ~8 independent row loads in flight per wave.
// MODE 0: xa[row] = bf16( x[row] + sum_nbr x[s] )
// MODE 1: BN of previous layer folded in (BN affine):
//         xa[row] = bf16( sc.(h[row]+sum h[s]) + (deg+1).sh )
// ---------------------------------------------------------------------------
template<int MODE>
__global__ __launch_bounds__(256) void gather_k(const u32* __restrict__ xb2,
                                                const int* __restrict__ offs,
                                                const int* __restrict__ deg,
                                                const int* __restrict__ slots,
                                                const float* __restrict__ stats_in,
                                                const float* __restrict__ g_in,
                                                const float* __restrict__ be_in,
                                                u32* __restrict__ xa2, int N)
{
    __shared__ float sc[128], sh[128];
    int t = threadIdx.x;
    if (MODE == 1) {
        if (t < 128) {
            float invN = 1.0f / (float)N;
            float mean = stats_in[t] * invN;
            float var  = stats_in[128 + t] * invN - mean * mean;
            float s = g_in[t] * rsqrtf(var + 1e-5f);
            sc[t] = s;
            sh[t] = be_in[t] - mean * s;
        }
        __syncthreads();
    }

    int row = blockIdx.x * 4 + (t >> 6);
    if (row >= N) return;
    int lane = t & 63;

    u32 self = xb2[(size_t)row * 64 + lane];
    float ax0 = bf_lo(self), ay0 = bf_hi(self);
    float ax1 = 0.f, ay1 = 0.f;

    int start = offs[row];
    int dg = deg[row];
    for (int base = 0; base < dg; base += 64) {
        int rem = dg - base;
        int m = rem < 64 ? rem : 64;
        int slot = (lane < m) ? slots[start + base + lane] : 0;
        int j = 0;
        for (; j + 8 <= m; j += 8) {
            int s0 = __shfl(slot, j + 0);
            int s1 = __shfl(slot, j + 1);
            int s2 = __shfl(slot, j + 2);
            int s3 = __shfl(slot, j + 3);
            int s4 = __shfl(slot, j + 4);
            int s5 = __shfl(slot, j + 5);
            int s6 = __shfl(slot, j + 6);
            int s7 = __shfl(slot, j + 7);
            u32 v0 = xb2[(size_t)s0 * 64 + lane];
            u32 v1 = xb2[(size_t)s1 * 64 + lane];
            u32 v2 = xb2[(size_t)s2 * 64 + lane];
            u32 v3 = xb2[(size_t)s3 * 64 + lane];
            u32 v4 = xb2[(size_t)s4 * 64 + lane];
            u32 v5 = xb2[(size_t)s5 * 64 + lane];
            u32 v6 = xb2[(size_t)s6 * 64 + lane];
            u32 v7 = xb2[(size_t)s7 * 64 + lane];
            ax0 += bf_lo(v0); ay0 += bf_hi(v0);
            ax1 += bf_lo(v1); ay1 += bf_hi(v1);
            ax0 += bf_lo(v2); ay0 += bf_hi(v2);
            ax1 += bf_lo(v3); ay1 += bf_hi(v3);
            ax0 += bf_lo(v4); ay0 += bf_hi(v4);
            ax1 += bf_lo(v5); ay1 += bf_hi(v5);
            ax0 += bf_lo(v6); ay0 += bf_hi(v6);
            ax1 += bf_lo(v7); ay1 += bf_hi(v7);
        }
        for (; j < m; ++j) {
            int s = __shfl(slot, j);
            u32 v = xb2[(size_t)s * 64 + lane];
            ax0 += bf_lo(v);
            ay0 += bf_hi(v);
        }
    }
    float ax = ax0 + ax1, ay = ay0 + ay1;
    if (MODE == 1) {
        float d1 = (float)(dg + 1);
        ax = sc[2 * lane]     * ax + d1 * sh[2 * lane];
        ay = sc[2 * lane + 1] * ay + d1 * sh[2 * lane + 1];
    }
    xa2[(size_t)row * 64 + lane] = pack2(ax, ay);
}

// ---------------------------------------------------------------------------
// fused MFMA MLP: h = relu(relu(XA@Wa + ba)@Wb + bb).
// BN stats go to a PER-BLOCK partial (coalesced 1KB store) instead of 400K
// contended global atomics (round<=7: the atomic drain was ~50us/dispatch).
// MODE 0: store bf16 h1.  MODE 1: store f32 h2.
// ---------------------------------------------------------------------------
template<int MODE>
__global__ __launch_bounds__(256) void mlp_mfma_k(
    const u16* __restrict__ xa,
    const u16* __restrict__ wfa, const float* __restrict__ ba,
    const u16* __restrict__ wfb, const float* __restrict__ bb,
    u16* __restrict__ hb_out, float* __restrict__ hf_out,
    float* __restrict__ partial, int N)
{
    __shared__ short ta[64 * 128];   // 16 KB tile (bf16, swizzled), reused
    __shared__ float ssum[256];

    int t = threadIdx.x;
    int w = t >> 6, l = t & 63;
    int row0 = blockIdx.x * 64;

    // stage XA tile (swizzled)
    for (int c = t; c < 1024; c += 256) {
        int r = c >> 4, ci = c & 15;
        int dst = (r * 128 + ci * 8) ^ ((r & 7) << 3);
        f32x4 v;
        if (row0 + r < N)
            v = *reinterpret_cast<const f32x4*>(xa + ((size_t)(row0 + r) * 128 + ci * 8));
        else
            v = f32x4{0.f, 0.f, 0.f, 0.f};
        *reinterpret_cast<f32x4*>(ta + dst) = v;
    }

    // W1 fragments for this wave's two 16-col blocks
    bf16x8 wf[2][4];
#pragma unroll
    for (int nr = 0; nr < 2; ++nr) {
        int nb = 2 * w + nr;
#pragma unroll
        for (int kg = 0; kg < 4; ++kg)
            wf[nr][kg] = *reinterpret_cast<const bf16x8*>(
                wfa + ((size_t)((kg * 8 + nb) * 64 + l)) * 8);
    }
    __syncthreads();

    int rr = l & 15;       // row within 16-tile
    int kg8 = l >> 4;      // k sub-group

    f32x4 acc[4][2];
#pragma unroll
    for (int mr = 0; mr < 4; ++mr)
#pragma unroll
        for (int nr = 0; nr < 2; ++nr)
            acc[mr][nr] = f32x4{0.f, 0.f, 0.f, 0.f};

#pragma unroll
    for (int mr = 0; mr < 4; ++mr) {
        int r = mr * 16 + rr;
        bf16x8 af[4];
#pragma unroll
        for (int kg = 0; kg < 4; ++kg) {
            int idx = (r * 128 + kg * 32 + kg8 * 8) ^ ((r & 7) << 3);
            af[kg] = *reinterpret_cast<const bf16x8*>(ta + idx);
        }
#pragma unroll
        for (int nr = 0; nr < 2; ++nr)
#pragma unroll
            for (int kg = 0; kg < 4; ++kg)
                acc[mr][nr] = __builtin_amdgcn_mfma_f32_16x16x32_bf16(
                    af[kg], wf[nr][kg], acc[mr][nr], 0, 0, 0);
    }
    __syncthreads();   // all GEMM1 reads of ta complete

    // bias + relu -> back into ta (bf16, swizzled)
    int colb = w * 32;
    float b0 = ba[colb + rr];
    float b1 = ba[colb + 16 + rr];
#pragma unroll
    for (int mr = 0; mr < 4; ++mr)
#pragma unroll
        for (int nr = 0; nr < 2; ++nr) {
            float bb_ = nr ? b1 : b0;
            int col = colb + nr * 16 + rr;
#pragma unroll
            for (int reg = 0; reg < 4; ++reg) {
                int row = mr * 16 + kg8 * 4 + reg;
                float v = fmaxf(acc[mr][nr][reg] + bb_, 0.0f);
                ta[(row * 128 + col) ^ ((row & 7) << 3)] = (short)f2bf(v);
            }
        }

    // W2 fragments
#pragma unroll
    for (int nr = 0; nr < 2; ++nr) {
        int nb = 2 * w + nr;
#pragma unroll
        for (int kg = 0; kg < 4; ++kg)
            wf[nr][kg] = *reinterpret_cast<const bf16x8*>(
                wfb + ((size_t)((kg * 8 + nb) * 64 + l)) * 8);
    }
    __syncthreads();   // intermediate tile fully written

#pragma unroll
    for (int mr = 0; mr < 4; ++mr)
#pragma unroll
        for (int nr = 0; nr < 2; ++nr)
            acc[mr][nr] = f32x4{0.f, 0.f, 0.f, 0.f};

#pragma unroll
    for (int mr = 0; mr < 4; ++mr) {
        int r = mr * 16 + rr;
        bf16x8 af[4];
#pragma unroll
        for (int kg = 0; kg < 4; ++kg) {
            int idx = (r * 128 + kg * 32 + kg8 * 8) ^ ((r & 7) << 3);
            af[kg] = *reinterpret_cast<const bf16x8*>(ta + idx);
        }
#pragma unroll
        for (int nr = 0; nr < 2; ++nr)
#pragma unroll
            for (int kg = 0; kg < 4; ++kg)
                acc[mr][nr] = __builtin_amdgcn_mfma_f32_16x16x32_bf16(
                    af[kg], wf[nr][kg], acc[mr][nr], 0, 0, 0);
    }

    // bias + relu + store + per-block BN stat partial
    float c0 = bb[colb + rr];
    float c1 = bb[colb + 16 + rr];
    float s0 = 0.f, q0 = 0.f, s1 = 0.f, q1 = 0.f;
#pragma unroll
    for (int mr = 0; mr < 4; ++mr) {
#pragma unroll
        for (int reg = 0; reg < 4; ++reg) {
            int row = row0 + mr * 16 + kg8 * 4 + reg;
            bool ok = row < N;
            float v0 = fmaxf(acc[mr][0][reg] + c0, 0.0f);
            float v1 = fmaxf(acc[mr][1][reg] + c1, 0.0f);
            if (ok) {
                if (MODE == 0) {
                    hb_out[(size_t)row * 128 + colb + rr]      = f2bf(v0);
                    hb_out[(size_t)row * 128 + colb + 16 + rr] = f2bf(v1);
                } else {
                    hf_out[(size_t)row * 128 + colb + rr]      = v0;
                    hf_out[(size_t)row * 128 + colb + 16 + rr] = v1;
                }
                s0 += v0; q0 += v0 * v0;
                s1 += v1; q1 += v1 * v1;
            }
        }
    }
    s0 += __shfl_xor(s0, 16); s0 += __shfl_xor(s0, 32);
    q0 += __shfl_xor(q0, 16); q0 += __shfl_xor(q0, 32);
    s1 += __shfl_xor(s1, 16); s1 += __shfl_xor(s1, 32);
    q1 += __shfl_xor(q1, 16); q1 += __shfl_xor(q1, 32);
    if (kg8 == 0) {            // each column owned by exactly one lane
        ssum[colb + rr]            = s0;
        ssum[128 + colb + rr]      = q0;
        ssum[colb + 16 + rr]       = s1;
        ssum[128 + colb + 16 + rr] = q1;
    }
    __syncthreads();
    partial[(size_t)blockIdx.x * 256 + t] = ssum[t];   // coalesced, no atomics
}

// ---------------------------------------------------------------------------
// reduce partials (nrows x 256) -> stats[256]; 32 blocks, 32 atomics/address
// ---------------------------------------------------------------------------
__global__ __launch_bounds__(256) void reduce_k(const float* __restrict__ partial,
                                                float* __restrict__ stats, int nrows)
{
    int t = threadIdx.x;
    int chunk = (nrows + gridDim.x - 1) / gridDim.x;
    int lo = blockIdx.x * chunk;
    int hi = lo + chunk; if (hi > nrows) hi = nrows;
    float acc = 0.f;
    for (int r = lo; r < hi; ++r)
        acc += partial[(size_t)r * 256 + t];
    if (hi > lo) atomicAdd(&stats[t], acc);
}

// ---------------------------------------------------------------------------
// final BN: in-place f32 on d_out
// ---------------------------------------------------------------------------
__global__ __launch_bounds__(256) void bn_apply_k(
    float* __restrict__ h, const float* __restrict__ stats,
    const float* __restrict__ gamma, const float* __restrict__ beta, int N)
{
    __shared__ float sc[128], sh[128];
    int t = threadIdx.x;
    if (t < 128) {
        float invN = 1.0f / (float)N;
        float mean = stats[t] * invN;
        float var  = stats[128 + t] * invN - mean * mean;
        float s = gamma[t] * rsqrtf(var + 1e-5f);
        sc[t] = s;
        sh[t] = beta[t] - mean * s;
    }
    __syncthreads();
    int total = N * 32;
    for (int i = blockIdx.x * 256 + t; i < total; i += gridDim.x * 256) {
        float4 v = reinterpret_cast<float4*>(h)[i];
        int c = (i & 31) * 4;
        v.x = v.x * sc[c + 0] + sh[c + 0];
        v.y = v.y * sc[c + 1] + sh[c + 1];
        v.z = v.z * sc[c + 2] + sh[c + 2];
        v.w = v.w * sc[c + 3] + sh[c + 3];
        reinterpret_cast<float4*>(h)[i] = v;
    }
}

// ---------------------------------------------------------------------------
extern "C" void kernel_launch(void* const* d_in, const int* in_sizes, int n_in,
                              void* d_out, int out_size, void* d_ws, size_t ws_size,
                              hipStream_t stream)
{
    const float* x   = (const float*)d_in[0];
    const int*   ei  = (const int*)d_in[1];
    const float* W1a = (const float*)d_in[2];
    const float* b1a = (const float*)d_in[3];
    const float* W1b = (const float*)d_in[4];
    const float* b1b = (const float*)d_in[5];
    const float* g1  = (const float*)d_in[6];
    const float* be1 = (const float*)d_in[7];
    const float* W2a = (const float*)d_in[8];
    const float* b2a = (const float*)d_in[9];
    const float* W2b = (const float*)d_in[10];
    const float* b2b = (const float*)d_in[11];
    const float* g2  = (const float*)d_in[12];
    const float* be2 = (const float*)d_in[13];

    const int N = in_sizes[0] / 128;
    const int E = in_sizes[1] / 2;
    const int* esrc = ei;
    const int* edst = ei + E;
    const int NB = (N + 127) >> 7;   // 128-row buckets; requires N <= 131072

    const int mblocks = (N + 63) / 64;
    const int gblocks = (N + 3) / 4;

    // ---- workspace carve ----
    char* p = (char*)d_ws;
    const size_t featb = (size_t)N * 128 * sizeof(u16);     // 25.6 MB
    u16* xa = (u16*)p;            p += featb;               // gather output
    u16* h1 = (u16*)p;            p += featb;               // layer-1 bf16 output
    u16* xb = (u16*)p;            p += featb;               // bf16 input features
    u16* wf = (u16*)p;            p += 4 * 16384 * sizeof(u16);
    int* slots = (int*)p;         p += (size_t)E * sizeof(int);
    int* deg   = (int*)p;         p += (size_t)N * sizeof(int);
    int* offs  = (int*)p;         p += (size_t)N * sizeof(int);
    int* gcount = (int*)p;        p += 1024 * sizeof(int);
    int* goffs  = (int*)p;        p += 1032 * sizeof(int);
    int* gcur   = (int*)p;        p += 1024 * sizeof(int);
    float* stats = (float*)p;     p += 512 * sizeof(float);
    float* partial = (float*)p;   p += (size_t)mblocks * 256 * sizeof(float);
    u32* bpacked = (u32*)xa;      // alias (E*4 = 6.4MB <= featb), dead early

    u16* wf1a = wf;
    u16* wf1b = wf + 16384;
    u16* wf2a = wf + 32768;
    u16* wf2b = wf + 49152;
    float* stats1 = stats;
    float* stats2 = stats + 256;

    float* h = (float*)d_out;

    // ---- one-time prep: bucket sort -> fine sort -> CSR; bf16 conversions ----
    hipMemsetAsync(gcount, 0, 1024 * sizeof(int), stream);
    bhist_k<<<256, 256, 0, stream>>>(edst, gcount, E, NB);
    bscan_k<<<1, 1024, 0, stream>>>(gcount, goffs, gcur, NB);
    bfill_k<<<256, 256, 0, stream>>>(esrc, edst, gcur, bpacked, E, NB);
    fsort_k<<<NB, 256, 0, stream>>>(bpacked, goffs, slots, offs, deg, N);
    convert_k<<<2048, 256, 0, stream>>>(x, (u32*)xb, N * 32);
    wprep_k<<<256, 256, 0, stream>>>(W1a, W1b, W2a, W2b, wf);
    hipMemsetAsync(stats, 0, 512 * sizeof(float), stream);

    // ---- layer 1: gather -> MLP (bf16 h1 + partial) -> reduce stats1 ----
    gather_k<0><<<gblocks, 256, 0, stream>>>((const u32*)xb, offs, deg, slots,
                                             nullptr, nullptr, nullptr, (u32*)xa, N);
    mlp_mfma_k<0><<<mblocks, 256, 0, stream>>>(xa, wf1a, b1a, wf1b, b1b,
                                               h1, (float*)nullptr, partial, N);
    reduce_k<<<32, 256, 0, stream>>>(partial, stats1, mblocks);

    // ---- layer 2: gather (BN1 folded) -> MLP (f32 h + partial) -> stats2 ----
    gather_k<1><<<gblocks, 256, 0, stream>>>((const u32*)h1, offs, deg, slots,
                                             stats1, g1, be1, (u32*)xa, N);
    mlp_mfma_k<1><<<mblocks, 256, 0, stream>>>(xa, wf2a, b2a, wf2b, b2b,
                                               (u16*)nullptr, h, partial, N);
    reduce_k<<<32, 256, 0, stream>>>(partial, stats2, mblocks);

    // ---- final BN in place on d_out ----
    bn_apply_k<<<2048, 256, 0, stream>>>(h, stats2, g2, be2, N);
}